// Round 2
// baseline (14839.725 us; speedup 1.0000x reference)
//
#include <hip/hip_runtime.h>
#include <hip/hip_bf16.h>

#define T_ 35
#define B_ 128
#define E_ 200
#define H_ 512
#define L_ 2
#define V_ 10000
#define BH_ (B_ * H_)

typedef __attribute__((ext_vector_type(8))) short bf16x8;
typedef __attribute__((ext_vector_type(4))) float f32x4;

__device__ __forceinline__ unsigned short f2bf(float f) {
    union { float f; unsigned u; } c; c.f = f;
    unsigned r = c.u + 0x7FFF + ((c.u >> 16) & 1);
    return (unsigned short)(r >> 16);
}

// Generic fused small-GEMM phase kernel:
// out[b][n] = epilogue( sum_{k<K1} A1[b][k]*W1[n][k] + sum_{k<512} A2'[b][k]*W2[n][k] + bias[n] )
// A1 row b = emb[idx[b]] if idx != null, else A1[b][K1].
// A2'[b][k] = A2[b][k] * (Rmul ? Rmul[b][k] : 1).
// mode 0: sigmoid -> Rout (n<512) / Fout (n>=512).   N = 1024, grid.y = 16
// mode 1: tanh -> hn = (1-f)*hp + f*tild -> HNout (+bf16 copy). N = 512, grid.y = 8
__global__ __launch_bounds__(256) void phase_kernel(
    const float* __restrict__ emb, const int* __restrict__ idx,
    const float* __restrict__ A1, int K1,
    const float* __restrict__ W1,     // [N][K1]
    const float* __restrict__ A2,     // [B][512]
    const float* __restrict__ Rmul,   // optional elementwise mult on A2
    const float* __restrict__ W2,     // [N][512]
    const float* __restrict__ bias,   // [N]
    int mode,
    float* __restrict__ Rout, float* __restrict__ Fout,
    const float* __restrict__ Fin, const float* __restrict__ HPold,
    float* __restrict__ HNout, unsigned short* __restrict__ h1bf)
{
    const int KT = 16, BM = 32, BN = 64;
    __shared__ float As[KT][BM + 1];
    __shared__ float Ws[KT][BN + 1];
    const int tid = threadIdx.x;
    const int bm0 = blockIdx.x * BM;
    const int bn0 = blockIdx.y * BN;
    const int Ktot = K1 + H_;

    const int tm0 = (tid >> 5) * 4;   // 0..28
    const int tn0 = (tid & 31) * 2;   // 0..62
    float acc[4][2] = {{0.f,0.f},{0.f,0.f},{0.f,0.f},{0.f,0.f}};

    for (int k0 = 0; k0 < Ktot; k0 += KT) {
        // A tile: 32 x 16
        {
            int i = tid;
            #pragma unroll
            for (int r = 0; r < 2; ++r, i += 256) {
                int m = i >> 4, kk = i & 15;
                int kg = k0 + kk;
                float v = 0.f;
                if (kg < Ktot) {
                    if (kg < K1) {
                        if (idx) { int row = idx[bm0 + m]; v = emb[row * E_ + kg]; }
                        else     { v = A1[(bm0 + m) * K1 + kg]; }
                    } else {
                        int k2 = kg - K1;
                        v = A2[(bm0 + m) * H_ + k2];
                        if (Rmul) v *= Rmul[(bm0 + m) * H_ + k2];
                    }
                }
                As[kk][m] = v;
            }
        }
        // W tile: 64 x 16
        {
            int i = tid;
            #pragma unroll
            for (int r = 0; r < 4; ++r, i += 256) {
                int n = i >> 4, kk = i & 15;
                int kg = k0 + kk;
                float v = 0.f;
                if (kg < Ktot) {
                    if (kg < K1) v = W1[(bn0 + n) * K1 + kg];
                    else         v = W2[(bn0 + n) * H_ + (kg - K1)];
                }
                Ws[kk][n] = v;
            }
        }
        __syncthreads();
        #pragma unroll
        for (int k = 0; k < KT; ++k) {
            float a0 = As[k][tm0 + 0], a1 = As[k][tm0 + 1];
            float a2 = As[k][tm0 + 2], a3 = As[k][tm0 + 3];
            float b0 = Ws[k][tn0 + 0], b1 = Ws[k][tn0 + 1];
            acc[0][0] += a0 * b0; acc[0][1] += a0 * b1;
            acc[1][0] += a1 * b0; acc[1][1] += a1 * b1;
            acc[2][0] += a2 * b0; acc[2][1] += a2 * b1;
            acc[3][0] += a3 * b0; acc[3][1] += a3 * b1;
        }
        __syncthreads();
    }

    #pragma unroll
    for (int i2 = 0; i2 < 4; ++i2) {
        int m = bm0 + tm0 + i2;
        #pragma unroll
        for (int j = 0; j < 2; ++j) {
            int n = bn0 + tn0 + j;
            float v = acc[i2][j] + bias[n];
            if (mode == 0) {
                float s = 1.f / (1.f + expf(-v));
                if (n < H_) Rout[m * H_ + n] = s;
                else        Fout[m * H_ + (n - H_)] = s;
            } else {
                float tld = tanhf(v);
                float f = Fin[m * H_ + n];
                float hp = HPold[m * H_ + n];
                float hn = (1.f - f) * hp + f * tld;
                HNout[m * H_ + n] = hn;
                if (h1bf) h1bf[m * H_ + n] = f2bf(hn);
            }
        }
    }
}

// Logits GEMM: C[m][v] = sum_h A[m][h]*Bw[v][h] + bias[v]
// A: [M=4480][K=512] bf16 row-major, Bw: [N=10000][K=512] bf16 (B^T layout).
// 128x128 tile / block of 4 waves, each wave 64x64 via 4x4 frags of 16x16x32 MFMA.
__global__ __launch_bounds__(256) void logits_gemm(
    const unsigned short* __restrict__ A,
    const unsigned short* __restrict__ Bw,
    const float* __restrict__ bias,
    float* __restrict__ C)
{
    const int K = H_;
    const int m0 = blockIdx.x * 128;
    const int n0 = blockIdx.y * 128;
    const int wave = threadIdx.x >> 6;
    const int lane = threadIdx.x & 63;
    const int wr = wave >> 1, wc = wave & 1;
    const int arow_base = m0 + wr * 64;
    const int bcol_base = n0 + wc * 64;

    f32x4 acc[4][4];
    f32x4 zero4 = {0.f, 0.f, 0.f, 0.f};
    #pragma unroll
    for (int i = 0; i < 4; ++i)
        #pragma unroll
        for (int j = 0; j < 4; ++j) acc[i][j] = zero4;

    const int lr = lane & 15;
    const int lk = (lane >> 4) * 8;
    bf16x8 zb = {0,0,0,0,0,0,0,0};

    for (int k0 = 0; k0 < K; k0 += 32) {
        bf16x8 a[4], b[4];
        #pragma unroll
        for (int i = 0; i < 4; ++i) {
            int row = arow_base + i * 16 + lr;
            a[i] = *(const bf16x8*)(A + (size_t)row * K + k0 + lk);
        }
        #pragma unroll
        for (int i = 0; i < 4; ++i) {
            int col = bcol_base + i * 16 + lr;
            b[i] = (col < V_) ? *(const bf16x8*)(Bw + (size_t)col * K + k0 + lk) : zb;
        }
        #pragma unroll
        for (int i = 0; i < 4; ++i)
            #pragma unroll
            for (int j = 0; j < 4; ++j)
                acc[i][j] = __builtin_amdgcn_mfma_f32_16x16x32_bf16(a[i], b[j], acc[i][j], 0, 0, 0);
    }

    // C/D layout (m89-verified): col = lane&15, row = (lane>>4)*4 + reg
    const int crow0 = (lane >> 4) * 4;
    const int ccol = lane & 15;
    #pragma unroll
    for (int j = 0; j < 4; ++j) {
        int col = bcol_base + j * 16 + ccol;
        if (col >= V_) continue;
        float bv = bias[col];
        #pragma unroll
        for (int i = 0; i < 4; ++i) {
            #pragma unroll
            for (int r = 0; r < 4; ++r) {
                int row = arow_base + i * 16 + crow0 + r;
                C[(size_t)row * V_ + col] = acc[i][j][r] + bv;
            }
        }
    }
}

__global__ void convert_wout(const float* __restrict__ W, unsigned short* __restrict__ Wb, int n) {
    int i = blockIdx.x * blockDim.x + threadIdx.x;
    if (i < n) Wb[i] = f2bf(W[i]);
}

__global__ void init_state(const float* __restrict__ hidden, float* __restrict__ hp0,
                           float* __restrict__ hp1, int bh) {
    int i = blockIdx.x * blockDim.x + threadIdx.x;
    if (i < bh) { hp0[i] = hidden[i]; hp1[i] = hidden[bh + i]; }
}

__global__ void write_hfinal(const float* __restrict__ hp0, const float* __restrict__ hp1,
                             float* __restrict__ out, int bh) {
    int i = blockIdx.x * blockDim.x + threadIdx.x;
    if (i < bh) { out[i] = hp0[i]; out[bh + i] = hp1[i]; }
}

extern "C" void kernel_launch(void* const* d_in, const int* in_sizes, int n_in,
                              void* d_out, int out_size, void* d_ws, size_t ws_size,
                              hipStream_t stream) {
    const int*   inputs = (const int*)  d_in[0];
    const float* hidden = (const float*)d_in[1];
    const float* emb    = (const float*)d_in[2];
    const float* Wx0    = (const float*)d_in[3];
    const float* Wx     = (const float*)d_in[4];
    const float* Wh     = (const float*)d_in[5];
    const float* bh     = (const float*)d_in[6];
    const float* Wout   = (const float*)d_in[7];
    const float* bout   = (const float*)d_in[8];
    float* out = (float*)d_out;

    char* ws = (char*)d_ws;
    size_t off = 0;
    auto alloc = [&](size_t bytes) -> void* {
        void* p = ws + off;
        off += (bytes + 255) & ~(size_t)255;
        return p;
    };
    unsigned short* WoutB = (unsigned short*)alloc((size_t)V_ * H_ * 2);
    unsigned short* h1bf  = (unsigned short*)alloc((size_t)T_ * B_ * H_ * 2);
    float* hp0b[2] = { (float*)alloc(BH_ * 4), (float*)alloc(BH_ * 4) };
    float* hp1b[2] = { (float*)alloc(BH_ * 4), (float*)alloc(BH_ * 4) };
    float* r0 = (float*)alloc(BH_ * 4);
    float* f0 = (float*)alloc(BH_ * 4);
    float* r1 = (float*)alloc(BH_ * 4);
    float* f1 = (float*)alloc(BH_ * 4);
    (void)ws_size; (void)in_sizes; (void)n_in; (void)out_size;

    convert_wout<<<dim3((V_ * H_ + 255) / 256), dim3(256), 0, stream>>>(Wout, WoutB, V_ * H_);
    init_state<<<dim3((BH_ + 255) / 256), dim3(256), 0, stream>>>(hidden, hp0b[0], hp1b[0], BH_);

    for (int t = 0; t < T_; ++t) {
        int cur = t & 1, nxt = cur ^ 1;
        const int* idx = inputs + t * B_;
        // Layer 0, phase 1: r0,f0 = sigmoid([x_t|hp0] @ [Wx0(g0,g1); Wh0(g0,g1)]^T + b)
        phase_kernel<<<dim3(4, 16), dim3(256), 0, stream>>>(
            emb, idx, nullptr, E_,
            Wx0, hp0b[cur], nullptr, Wh, bh, 0,
            r0, f0, nullptr, nullptr, nullptr, nullptr);
        // Layer 0, phase 2: hn0 = blend(tanh([x_t|r0*hp0] @ [Wx0(g2); Wh0(g2)]^T + b))
        phase_kernel<<<dim3(4, 8), dim3(256), 0, stream>>>(
            emb, idx, nullptr, E_,
            Wx0 + 2 * H_ * E_, hp0b[cur], r0, Wh + 2 * H_ * H_, bh + 2 * H_, 1,
            nullptr, nullptr, f0, hp0b[cur], hp0b[nxt], nullptr);
        // Layer 1, phase 1
        phase_kernel<<<dim3(4, 16), dim3(256), 0, stream>>>(
            nullptr, nullptr, hp0b[nxt], H_,
            Wx, hp1b[cur], nullptr, Wh + 3 * H_ * H_, bh + 3 * H_, 0,
            r1, f1, nullptr, nullptr, nullptr, nullptr);
        // Layer 1, phase 2 (also emits bf16 h1 row block for the logits GEMM)
        phase_kernel<<<dim3(4, 8), dim3(256), 0, stream>>>(
            nullptr, nullptr, hp0b[nxt], H_,
            Wx + 2 * H_ * H_, hp1b[cur], r1, Wh + 3 * H_ * H_ + 2 * H_ * H_,
            bh + 3 * H_ + 2 * H_, 1,
            nullptr, nullptr, f1, hp1b[cur], hp1b[nxt], h1bf + (size_t)t * B_ * H_);
    }

    logits_gemm<<<dim3(T_ * B_ / 128, (V_ + 127) / 128), dim3(256), 0, stream>>>(
        h1bf, WoutB, bout, out);
    write_hfinal<<<dim3((BH_ + 255) / 256), dim3(256), 0, stream>>>(
        hp0b[1], hp1b[1], out + (size_t)T_ * B_ * V_, BH_);
}

// Round 3
// 3617.151 us; speedup vs baseline: 4.1026x; 4.1026x over previous
//
#include <hip/hip_runtime.h>
#include <hip/hip_bf16.h>

#define T_ 35
#define B_ 128
#define E_ 200
#define H_ 512
#define L_ 2
#define V_ 10000
#define BH_ (B_ * H_)
#define KPAD 224
#define NWG 64

typedef __attribute__((ext_vector_type(8))) short bf16x8;
typedef __attribute__((ext_vector_type(4))) float f32x4;

__device__ __forceinline__ unsigned short f2bf(float f) {
    union { float f; unsigned u; } c; c.f = f;
    unsigned r = c.u + 0x7FFF + ((c.u >> 16) & 1);
    return (unsigned short)(r >> 16);
}

// ---------------------------------------------------------------- prep
// job 0: embB [V][224] bf16 (pad 200..223 = 0)
// job 1: wx0cat [1536][224] bf16 from Wx0 (rows g*512+h)
// job 2: whl0rf [1024][512] bf16 = Wh[0][0..1]
// job 3: whl0c  [512][512]  bf16 = Wh[0][2]
// job 4: w1rf [1024][1024] bf16 = [Wx[0][g] | Wh[1][g]], g=0,1
// job 5: w1c  [512][1024]  bf16 = [Wx[0][2] | Wh[1][2]]
// job 6: init state from hidden; zero barrier
__global__ void prep_all(const float* __restrict__ emb, const float* __restrict__ Wx0,
                         const float* __restrict__ Wx, const float* __restrict__ Wh,
                         const float* __restrict__ hidden,
                         unsigned short* embB, unsigned short* wx0cat,
                         unsigned short* whl0rf, unsigned short* whl0c,
                         unsigned short* w1rf, unsigned short* w1c,
                         float* h0f, unsigned short* h0b1,
                         float* h1f, unsigned short* h1b, int* bar) {
    int job = blockIdx.y;
    int stride = gridDim.x * blockDim.x;
    int i0 = blockIdx.x * blockDim.x + threadIdx.x;
    if (job == 0) {
        for (int i = i0; i < V_ * KPAD; i += stride) {
            int v = i / KPAD, k = i - v * KPAD;
            embB[i] = (k < E_) ? f2bf(emb[v * E_ + k]) : (unsigned short)0;
        }
    } else if (job == 1) {
        for (int i = i0; i < 1536 * KPAD; i += stride) {
            int n = i / KPAD, k = i - n * KPAD;
            wx0cat[i] = (k < E_) ? f2bf(Wx0[n * E_ + k]) : (unsigned short)0;
        }
    } else if (job == 2) {
        for (int i = i0; i < 1024 * 512; i += stride) whl0rf[i] = f2bf(Wh[i]);
    } else if (job == 3) {
        for (int i = i0; i < 512 * 512; i += stride) whl0c[i] = f2bf(Wh[524288 + i]);
    } else if (job == 4) {
        for (int i = i0; i < 1024 * 1024; i += stride) {
            int n = i >> 10, k = i & 1023;
            w1rf[i] = (k < 512) ? f2bf(Wx[n * 512 + k])
                                : f2bf(Wh[786432 + n * 512 + (k - 512)]);
        }
    } else if (job == 5) {
        for (int i = i0; i < 512 * 1024; i += stride) {
            int n = i >> 10, k = i & 1023;
            w1c[i] = (k < 512) ? f2bf(Wx[524288 + n * 512 + k])
                               : f2bf(Wh[1310720 + n * 512 + (k - 512)]);
        }
    } else {
        for (int i = i0; i < 2 * BH_; i += stride) {
            if (i < BH_) { h0f[i] = hidden[i]; h0b1[i] = f2bf(hidden[i]); }
            else { int k = i - BH_; h1f[k] = hidden[i]; h1b[k] = f2bf(hidden[i]); }
        }
        if (i0 == 0) bar[0] = 0;
    }
}

// ---------------------------------------------------------------- x-side GEMM
// gx0[t][g][b][h] = sum_e emb[inputs[t][b]][e] * Wx0[g][h][e]
// M=4480 (t*128+b), N=1536 (g*512+h), K=224 (padded). 128x128 tile / 4 waves.
__global__ __launch_bounds__(256) void xside_gemm(
    const int* __restrict__ inputs, const unsigned short* __restrict__ embB,
    const unsigned short* __restrict__ wx0cat, float* __restrict__ gx0) {
    int m0 = blockIdx.x * 128, n0 = blockIdx.y * 128;
    int wave = threadIdx.x >> 6, lane = threadIdx.x & 63;
    int wr = wave >> 1, wc = wave & 1;
    int am = m0 + wr * 64, bn = n0 + wc * 64;
    int lr = lane & 15, lk = (lane >> 4) * 8;

    f32x4 acc[4][4] = {};
    int id[4];
    #pragma unroll
    for (int i = 0; i < 4; ++i) id[i] = inputs[am + i * 16 + lr];

    for (int k0 = 0; k0 < KPAD; k0 += 32) {
        bf16x8 a[4], b[4];
        #pragma unroll
        for (int i = 0; i < 4; ++i)
            a[i] = *(const bf16x8*)(embB + (size_t)id[i] * KPAD + k0 + lk);
        #pragma unroll
        for (int j = 0; j < 4; ++j)
            b[j] = *(const bf16x8*)(wx0cat + (size_t)(bn + j * 16 + lr) * KPAD + k0 + lk);
        #pragma unroll
        for (int i = 0; i < 4; ++i)
            #pragma unroll
            for (int j = 0; j < 4; ++j)
                acc[i][j] = __builtin_amdgcn_mfma_f32_16x16x32_bf16(a[i], b[j], acc[i][j], 0, 0, 0);
    }
    int crow0 = (lane >> 4) * 4, ccol = lane & 15;
    #pragma unroll
    for (int i = 0; i < 4; ++i) {
        #pragma unroll
        for (int r = 0; r < 4; ++r) {
            int row = am + i * 16 + crow0 + r;
            int t = row >> 7, b = row & 127;
            #pragma unroll
            for (int j = 0; j < 4; ++j) {
                int col = bn + j * 16 + ccol;
                int g = col >> 9, h = col & 511;
                gx0[((size_t)(t * 3 + g) * 128 + b) * 512 + h] = acc[i][j][r];
            }
        }
    }
}

// ---------------------------------------------------------------- scan
__device__ __forceinline__ void grid_bar(int* bar, int gen) {
    __threadfence();     // release: my stores visible device-wide
    __syncthreads();
    if (threadIdx.x == 0) {
        __hip_atomic_fetch_add(bar, 1, __ATOMIC_RELEASE, __HIP_MEMORY_SCOPE_AGENT);
        while (__hip_atomic_load(bar, __ATOMIC_ACQUIRE, __HIP_MEMORY_SCOPE_AGENT) < gen * NWG)
            __builtin_amdgcn_s_sleep(1);
    }
    __syncthreads();
    __threadfence();     // acquire: discard stale cached data
}

// one 16x64 wave-tile K-accumulate; A rows stride 512 (concat A1|A2 when K=1024)
template<int K>
__device__ __forceinline__ void mfma_acc(f32x4 acc[4], const unsigned short* A1,
                                         const unsigned short* A2, const unsigned short* W,
                                         int arow, int bcol0, int lane) {
    const int lr = lane & 15, lk = (lane >> 4) * 8;
    #pragma unroll
    for (int k0 = 0; k0 < K; k0 += 32) {
        const unsigned short* ap = (k0 < 512) ? (A1 + arow * 512 + k0 + lk)
                                              : (A2 + arow * 512 + (k0 - 512) + lk);
        bf16x8 a = *(const bf16x8*)ap;
        #pragma unroll
        for (int j = 0; j < 4; ++j) {
            bf16x8 b = *(const bf16x8*)(W + (size_t)(bcol0 + j * 16 + lr) * K + k0 + lk);
            acc[j] = __builtin_amdgcn_mfma_f32_16x16x32_bf16(a, b, acc[j], 0, 0, 0);
        }
    }
}

// Persistent 2-layer pipelined GRU scan. 64 WGs x 256 threads.
// slot 2t  : L0-P1(t)  [wg 0..31]  || L1-P1(t-1) [wg 32..63]
// slot 2t+1: L0-P2(t)  [wg 0..15]  || L1-P2(t-1) [wg 16..31]
__global__ __launch_bounds__(256) void scan_kernel(
    const float* __restrict__ gx0,
    const unsigned short* __restrict__ whl0rf, const unsigned short* __restrict__ whl0c,
    const unsigned short* __restrict__ w1rf, const unsigned short* __restrict__ w1c,
    const float* __restrict__ bh,
    float* h0f, unsigned short* h0b0, unsigned short* h0b1,
    float* h1f, unsigned short* h1b,
    unsigned short* rh0b, float* f0buf,
    unsigned short* rh1b, float* f1buf,
    unsigned short* h1bf, int* bar) {
    const int wg = blockIdx.x;
    const int lane = threadIdx.x & 63;
    const int wave = threadIdx.x >> 6;
    const int wr = wave >> 1, wc = wave & 1;
    const int ccol = lane & 15, crow0 = (lane >> 4) * 4, lr = lane & 15;

    for (int s = 0; s <= 2 * T_ + 1; ++s) {
        if ((s & 1) == 0) {
            int t = s >> 1;
            if (wg < 32) {
                if (t < T_) {  // L0-P1(t): r,f gates
                    int bm0 = (wg & 3) * 32, bn0 = (wg >> 2) * 128;
                    int bm = bm0 + wr * 16, bc = bn0 + wc * 64;
                    const unsigned short* hprev = (t & 1) ? h0b0 : h0b1;
                    f32x4 acc[4] = {};
                    mfma_acc<512>(acc, hprev, hprev, whl0rf, bm + lr, bc, lane);
                    #pragma unroll
                    for (int j = 0; j < 4; ++j) {
                        int col = bc + j * 16 + ccol;
                        int g = col >> 9, h = col & 511;
                        float bias = bh[g * 512 + h];
                        const float* gx = gx0 + (size_t)(t * 3 + g) * BH_ + h;
                        #pragma unroll
                        for (int r = 0; r < 4; ++r) {
                            int b = bm + crow0 + r;
                            float v = acc[j][r] + gx[b * 512] + bias;
                            float sg = 1.f / (1.f + __expf(-v));
                            if (g == 0) rh0b[b * 512 + h] = f2bf(sg * h0f[b * 512 + h]);
                            else        f0buf[b * 512 + h] = sg;
                        }
                    }
                }
            } else {
                int tc = t - 1;
                if (tc >= 0 && tc < T_) {  // L1-P1(tc)
                    int wid = wg - 32;
                    int bm0 = (wid & 3) * 32, bn0 = (wid >> 2) * 128;
                    int bm = bm0 + wr * 16, bc = bn0 + wc * 64;
                    const unsigned short* h0cur = (tc & 1) ? h0b1 : h0b0;
                    f32x4 acc[4] = {};
                    mfma_acc<1024>(acc, h0cur, h1b, w1rf, bm + lr, bc, lane);
                    #pragma unroll
                    for (int j = 0; j < 4; ++j) {
                        int col = bc + j * 16 + ccol;
                        int g = col >> 9, h = col & 511;
                        float bias = bh[1536 + g * 512 + h];
                        #pragma unroll
                        for (int r = 0; r < 4; ++r) {
                            int b = bm + crow0 + r;
                            float v = acc[j][r] + bias;
                            float sg = 1.f / (1.f + __expf(-v));
                            if (g == 0) rh1b[b * 512 + h] = f2bf(sg * h1f[b * 512 + h]);
                            else        f1buf[b * 512 + h] = sg;
                        }
                    }
                }
            }
        } else {
            int t = s >> 1;
            if (wg < 16) {
                if (t < T_) {  // L0-P2(t): candidate + blend
                    int bm0 = (wg & 3) * 32, bn0 = (wg >> 2) * 128;
                    int bm = bm0 + wr * 16, bc = bn0 + wc * 64;
                    unsigned short* h0bw = (t & 1) ? h0b1 : h0b0;
                    f32x4 acc[4] = {};
                    mfma_acc<512>(acc, rh0b, rh0b, whl0c, bm + lr, bc, lane);
                    #pragma unroll
                    for (int j = 0; j < 4; ++j) {
                        int h = bc + j * 16 + ccol;
                        float bias = bh[1024 + h];
                        const float* gx = gx0 + (size_t)(t * 3 + 2) * BH_ + h;
                        #pragma unroll
                        for (int r = 0; r < 4; ++r) {
                            int b = bm + crow0 + r;
                            float v = acc[j][r] + gx[b * 512] + bias;
                            float tld = tanhf(v);
                            float hp = h0f[b * 512 + h];
                            float f = f0buf[b * 512 + h];
                            float hn = hp + f * (tld - hp);
                            h0f[b * 512 + h] = hn;
                            h0bw[b * 512 + h] = f2bf(hn);
                        }
                    }
                }
            } else if (wg < 32) {
                int tc = t - 1;
                if (tc >= 0 && tc < T_) {  // L1-P2(tc)
                    int wid = wg - 16;
                    int bm0 = (wid & 3) * 32, bn0 = (wid >> 2) * 128;
                    int bm = bm0 + wr * 16, bc = bn0 + wc * 64;
                    const unsigned short* h0cur = (tc & 1) ? h0b1 : h0b0;
                    f32x4 acc[4] = {};
                    mfma_acc<1024>(acc, h0cur, rh1b, w1c, bm + lr, bc, lane);
                    #pragma unroll
                    for (int j = 0; j < 4; ++j) {
                        int h = bc + j * 16 + ccol;
                        float bias = bh[2560 + h];
                        #pragma unroll
                        for (int r = 0; r < 4; ++r) {
                            int b = bm + crow0 + r;
                            float v = acc[j][r] + bias;
                            float tld = tanhf(v);
                            float hp = h1f[b * 512 + h];
                            float f = f1buf[b * 512 + h];
                            float hn = hp + f * (tld - hp);
                            h1f[b * 512 + h] = hn;
                            unsigned short hb = f2bf(hn);
                            h1b[b * 512 + h] = hb;
                            h1bf[(size_t)tc * BH_ + b * 512 + h] = hb;
                        }
                    }
                }
            }
        }
        grid_bar(bar, s + 1);
    }
}

// ---------------------------------------------------------------- logits
// C[m][v] = sum_h h1bf[m][h] * Wout[v][h] + bout[v]; Wout f32 -> bf16 inline.
__global__ __launch_bounds__(256) void logits_gemm(
    const unsigned short* __restrict__ A, const float* __restrict__ Wout,
    const float* __restrict__ bout, float* __restrict__ C) {
    const int K = H_;
    int m0 = blockIdx.x * 128, n0 = blockIdx.y * 128;
    int wave = threadIdx.x >> 6, lane = threadIdx.x & 63;
    int wr = wave >> 1, wc = wave & 1;
    int am = m0 + wr * 64, bn = n0 + wc * 64;
    int lr = lane & 15, lk = (lane >> 4) * 8;

    f32x4 acc[4][4] = {};
    for (int k0 = 0; k0 < K; k0 += 32) {
        bf16x8 a[4], b[4];
        #pragma unroll
        for (int i = 0; i < 4; ++i)
            a[i] = *(const bf16x8*)(A + (size_t)(am + i * 16 + lr) * K + k0 + lk);
        #pragma unroll
        for (int j = 0; j < 4; ++j) {
            int colc = bn + j * 16 + lr; if (colc >= V_) colc = V_ - 1;
            const float* wp = Wout + (size_t)colc * K + k0 + lk;
            float4 w0 = *(const float4*)wp;
            float4 w1 = *(const float4*)(wp + 4);
            bf16x8 bb;
            bb[0] = (short)f2bf(w0.x); bb[1] = (short)f2bf(w0.y);
            bb[2] = (short)f2bf(w0.z); bb[3] = (short)f2bf(w0.w);
            bb[4] = (short)f2bf(w1.x); bb[5] = (short)f2bf(w1.y);
            bb[6] = (short)f2bf(w1.z); bb[7] = (short)f2bf(w1.w);
            b[j] = bb;
        }
        #pragma unroll
        for (int i = 0; i < 4; ++i)
            #pragma unroll
            for (int j = 0; j < 4; ++j)
                acc[i][j] = __builtin_amdgcn_mfma_f32_16x16x32_bf16(a[i], b[j], acc[i][j], 0, 0, 0);
    }
    int crow0 = (lane >> 4) * 4, ccol = lane & 15;
    #pragma unroll
    for (int j = 0; j < 4; ++j) {
        int col = bn + j * 16 + ccol;
        if (col >= V_) continue;
        float bv = bout[col];
        #pragma unroll
        for (int i = 0; i < 4; ++i) {
            #pragma unroll
            for (int r = 0; r < 4; ++r) {
                int row = am + i * 16 + crow0 + r;
                __builtin_nontemporal_store(acc[i][j][r] + bv, &C[(size_t)row * V_ + col]);
            }
        }
    }
}

__global__ void write_hfinal(const float* __restrict__ h0f, const float* __restrict__ h1f,
                             float* __restrict__ out) {
    int i = blockIdx.x * blockDim.x + threadIdx.x;
    if (i < BH_) { out[i] = h0f[i]; out[BH_ + i] = h1f[i]; }
}

// ---------------------------------------------------------------- launch
extern "C" void kernel_launch(void* const* d_in, const int* in_sizes, int n_in,
                              void* d_out, int out_size, void* d_ws, size_t ws_size,
                              hipStream_t stream) {
    const int*   inputs = (const int*)  d_in[0];
    const float* hidden = (const float*)d_in[1];
    const float* emb    = (const float*)d_in[2];
    const float* Wx0    = (const float*)d_in[3];
    const float* Wx     = (const float*)d_in[4];
    const float* Wh     = (const float*)d_in[5];
    const float* bh     = (const float*)d_in[6];
    const float* Wout   = (const float*)d_in[7];
    const float* bout   = (const float*)d_in[8];
    float* out = (float*)d_out;
    (void)in_sizes; (void)n_in; (void)out_size; (void)ws_size;

    char* ws = (char*)d_ws;
    size_t off = 0;
    auto alloc = [&](size_t bytes) -> void* {
        void* p = ws + off;
        off += (bytes + 255) & ~(size_t)255;
        return p;
    };
    unsigned short* embB   = (unsigned short*)alloc((size_t)V_ * KPAD * 2);
    unsigned short* wx0cat = (unsigned short*)alloc((size_t)1536 * KPAD * 2);
    unsigned short* whl0rf = (unsigned short*)alloc((size_t)1024 * 512 * 2);
    unsigned short* whl0c  = (unsigned short*)alloc((size_t)512 * 512 * 2);
    unsigned short* w1rf   = (unsigned short*)alloc((size_t)1024 * 1024 * 2);
    unsigned short* w1c    = (unsigned short*)alloc((size_t)512 * 1024 * 2);
    unsigned short* h1bf   = (unsigned short*)alloc((size_t)T_ * BH_ * 2);
    float* h0f  = (float*)alloc(BH_ * 4);
    float* h1f  = (float*)alloc(BH_ * 4);
    unsigned short* h0b0 = (unsigned short*)alloc(BH_ * 2);
    unsigned short* h0b1 = (unsigned short*)alloc(BH_ * 2);
    unsigned short* h1b  = (unsigned short*)alloc(BH_ * 2);
    unsigned short* rh0b = (unsigned short*)alloc(BH_ * 2);
    unsigned short* rh1b = (unsigned short*)alloc(BH_ * 2);
    float* f0buf = (float*)alloc(BH_ * 4);
    float* f1buf = (float*)alloc(BH_ * 4);
    int* bar = (int*)alloc(256);

    // gx0 [T][3][128][512] f32 lives in d_out (27.5 MB); overwritten by logits later.
    float* gx0 = out;

    prep_all<<<dim3(1024, 7), dim3(256), 0, stream>>>(
        emb, Wx0, Wx, Wh, hidden, embB, wx0cat, whl0rf, whl0c, w1rf, w1c,
        h0f, h0b1, h1f, h1b, bar);
    xside_gemm<<<dim3(T_, 12), dim3(256), 0, stream>>>(inputs, embB, wx0cat, gx0);
    scan_kernel<<<dim3(NWG), dim3(256), 0, stream>>>(
        gx0, whl0rf, whl0c, w1rf, w1c, bh,
        h0f, h0b0, h0b1, h1f, h1b, rh0b, f0buf, rh1b, f1buf, h1bf, bar);
    logits_gemm<<<dim3(T_ * B_ / 128, (V_ + 127) / 128), dim3(256), 0, stream>>>(
        h1bf, Wout, bout, out);
    write_hfinal<<<dim3((BH_ + 255) / 256), dim3(256), 0, stream>>>(
        h0f, h1f, out + (size_t)T_ * B_ * V_);
}

// Round 4
// 2551.151 us; speedup vs baseline: 5.8169x; 1.4179x over previous
//
#include <hip/hip_runtime.h>
#include <hip/hip_bf16.h>

#define T_ 35
#define B_ 128
#define E_ 200
#define H_ 512
#define L_ 2
#define V_ 10000
#define BH_ (B_ * H_)
#define KPAD 224
#define NWG 64

typedef __attribute__((ext_vector_type(8))) short bf16x8;
typedef __attribute__((ext_vector_type(4))) float f32x4;

__device__ __forceinline__ unsigned short f2bf(float f) {
    union { float f; unsigned u; } c; c.f = f;
    unsigned r = c.u + 0x7FFF + ((c.u >> 16) & 1);
    return (unsigned short)(r >> 16);
}

// ---------------------------------------------------------------- prep
__global__ void prep_all(const float* __restrict__ emb, const float* __restrict__ Wx0,
                         const float* __restrict__ Wx, const float* __restrict__ Wh,
                         const float* __restrict__ hidden,
                         unsigned short* embB, unsigned short* wx0cat,
                         unsigned short* whl0rf, unsigned short* whl0c,
                         unsigned short* w1rf, unsigned short* w1c,
                         float* h0f, unsigned short* h0b1,
                         float* h1f, unsigned short* h1b, int* bar) {
    int job = blockIdx.y;
    int stride = gridDim.x * blockDim.x;
    int i0 = blockIdx.x * blockDim.x + threadIdx.x;
    if (job == 0) {
        for (int i = i0; i < V_ * KPAD; i += stride) {
            int v = i / KPAD, k = i - v * KPAD;
            embB[i] = (k < E_) ? f2bf(emb[v * E_ + k]) : (unsigned short)0;
        }
    } else if (job == 1) {
        for (int i = i0; i < 1536 * KPAD; i += stride) {
            int n = i / KPAD, k = i - n * KPAD;
            wx0cat[i] = (k < E_) ? f2bf(Wx0[n * E_ + k]) : (unsigned short)0;
        }
    } else if (job == 2) {
        for (int i = i0; i < 1024 * 512; i += stride) whl0rf[i] = f2bf(Wh[i]);
    } else if (job == 3) {
        for (int i = i0; i < 512 * 512; i += stride) whl0c[i] = f2bf(Wh[524288 + i]);
    } else if (job == 4) {
        for (int i = i0; i < 1024 * 1024; i += stride) {
            int n = i >> 10, k = i & 1023;
            w1rf[i] = (k < 512) ? f2bf(Wx[n * 512 + k])
                                : f2bf(Wh[786432 + n * 512 + (k - 512)]);
        }
    } else if (job == 5) {
        for (int i = i0; i < 512 * 1024; i += stride) {
            int n = i >> 10, k = i & 1023;
            w1c[i] = (k < 512) ? f2bf(Wx[524288 + n * 512 + k])
                               : f2bf(Wh[1310720 + n * 512 + (k - 512)]);
        }
    } else {
        for (int i = i0; i < 2 * BH_; i += stride) {
            if (i < BH_) { h0f[i] = hidden[i]; h0b1[i] = f2bf(hidden[i]); }
            else { int k = i - BH_; h1f[k] = hidden[i]; h1b[k] = f2bf(hidden[i]); }
        }
        if (i0 == 0) bar[0] = 0;
    }
}

// ---------------------------------------------------------------- x-side GEMM
__global__ __launch_bounds__(256) void xside_gemm(
    const int* __restrict__ inputs, const unsigned short* __restrict__ embB,
    const unsigned short* __restrict__ wx0cat, float* __restrict__ gx0) {
    int m0 = blockIdx.x * 128, n0 = blockIdx.y * 128;
    int wave = threadIdx.x >> 6, lane = threadIdx.x & 63;
    int wr = wave >> 1, wc = wave & 1;
    int am = m0 + wr * 64, bn = n0 + wc * 64;
    int lr = lane & 15, lk = (lane >> 4) * 8;

    f32x4 acc[4][4] = {};
    int id[4];
    #pragma unroll
    for (int i = 0; i < 4; ++i) id[i] = inputs[am + i * 16 + lr];

    for (int k0 = 0; k0 < KPAD; k0 += 32) {
        bf16x8 a[4], b[4];
        #pragma unroll
        for (int i = 0; i < 4; ++i)
            a[i] = *(const bf16x8*)(embB + (size_t)id[i] * KPAD + k0 + lk);
        #pragma unroll
        for (int j = 0; j < 4; ++j)
            b[j] = *(const bf16x8*)(wx0cat + (size_t)(bn + j * 16 + lr) * KPAD + k0 + lk);
        #pragma unroll
        for (int i = 0; i < 4; ++i)
            #pragma unroll
            for (int j = 0; j < 4; ++j)
                acc[i][j] = __builtin_amdgcn_mfma_f32_16x16x32_bf16(a[i], b[j], acc[i][j], 0, 0, 0);
    }
    int crow0 = (lane >> 4) * 4, ccol = lane & 15;
    #pragma unroll
    for (int i = 0; i < 4; ++i) {
        #pragma unroll
        for (int r = 0; r < 4; ++r) {
            int row = am + i * 16 + crow0 + r;
            int t = row >> 7, b = row & 127;
            #pragma unroll
            for (int j = 0; j < 4; ++j) {
                int col = bn + j * 16 + ccol;
                int g = col >> 9, h = col & 511;
                gx0[((size_t)(t * 3 + g) * 128 + b) * 512 + h] = acc[i][j][r];
            }
        }
    }
}

// ---------------------------------------------------------------- scan
// Minimal-cost grid barrier: one release-RMW per WG (thread 0 only; its
// release writes back this XCD's dirty L2 once), RELAXED polling (agent-
// coherent load, no cache maintenance per poll), and exactly one acquire
// fence (L1/L2 invalidate) per thread per slot, after the closing barrier.
__device__ __forceinline__ void grid_bar(int* bar, int gen) {
    __syncthreads();   // all waves' stores drained (compiler emits vmcnt(0))
    if (threadIdx.x == 0) {
        __hip_atomic_fetch_add(bar, 1, __ATOMIC_RELEASE, __HIP_MEMORY_SCOPE_AGENT);
        while (__hip_atomic_load(bar, __ATOMIC_RELAXED, __HIP_MEMORY_SCOPE_AGENT) < gen * NWG)
            __builtin_amdgcn_s_sleep(1);
    }
    __syncthreads();
    __builtin_amdgcn_fence(__ATOMIC_ACQUIRE, "agent");
}

template<int K>
__device__ __forceinline__ void mfma_acc(f32x4 acc[4], const unsigned short* A1,
                                         const unsigned short* A2, const unsigned short* W,
                                         int arow, int bcol0, int lane) {
    const int lr = lane & 15, lk = (lane >> 4) * 8;
    #pragma unroll
    for (int k0 = 0; k0 < K; k0 += 32) {
        const unsigned short* ap = (k0 < 512) ? (A1 + arow * 512 + k0 + lk)
                                              : (A2 + arow * 512 + (k0 - 512) + lk);
        bf16x8 a = *(const bf16x8*)ap;
        #pragma unroll
        for (int j = 0; j < 4; ++j) {
            bf16x8 b = *(const bf16x8*)(W + (size_t)(bcol0 + j * 16 + lr) * K + k0 + lk);
            acc[j] = __builtin_amdgcn_mfma_f32_16x16x32_bf16(a, b, acc[j], 0, 0, 0);
        }
    }
}

// Persistent 2-layer pipelined GRU scan. 64 WGs x 256 threads.
// slot 2t  : L0-P1(t)  [wg 0..31]  || L1-P1(t-1) [wg 32..63]
// slot 2t+1: L0-P2(t)  [wg 0..15]  || L1-P2(t-1) [wg 16..31]
__global__ __launch_bounds__(256) void scan_kernel(
    const float* __restrict__ gx0,
    const unsigned short* __restrict__ whl0rf, const unsigned short* __restrict__ whl0c,
    const unsigned short* __restrict__ w1rf, const unsigned short* __restrict__ w1c,
    const float* __restrict__ bh,
    float* h0f, unsigned short* h0b0, unsigned short* h0b1,
    float* h1f, unsigned short* h1b,
    unsigned short* rh0b, float* f0buf,
    unsigned short* rh1b, float* f1buf,
    unsigned short* h1bf, int* bar, float* hfinal_out) {
    const int wg = blockIdx.x;
    const int lane = threadIdx.x & 63;
    const int wave = threadIdx.x >> 6;
    const int wr = wave >> 1, wc = wave & 1;
    const int ccol = lane & 15, crow0 = (lane >> 4) * 4, lr = lane & 15;

    for (int s = 0; s <= 2 * T_ + 1; ++s) {
        if ((s & 1) == 0) {
            int t = s >> 1;
            if (wg < 32) {
                if (t < T_) {  // L0-P1(t): r,f gates
                    int bm0 = (wg & 3) * 32, bn0 = (wg >> 2) * 128;
                    int bm = bm0 + wr * 16, bc = bn0 + wc * 64;
                    const unsigned short* hprev = (t & 1) ? h0b0 : h0b1;
                    f32x4 acc[4] = {};
                    mfma_acc<512>(acc, hprev, hprev, whl0rf, bm + lr, bc, lane);
                    #pragma unroll
                    for (int j = 0; j < 4; ++j) {
                        int col = bc + j * 16 + ccol;
                        int g = col >> 9, h = col & 511;
                        float bias = bh[g * 512 + h];
                        const float* gx = gx0 + (size_t)(t * 3 + g) * BH_ + h;
                        #pragma unroll
                        for (int r = 0; r < 4; ++r) {
                            int b = bm + crow0 + r;
                            float v = acc[j][r] + gx[b * 512] + bias;
                            float sg = 1.f / (1.f + __expf(-v));
                            if (g == 0) rh0b[b * 512 + h] = f2bf(sg * h0f[b * 512 + h]);
                            else        f0buf[b * 512 + h] = sg;
                        }
                    }
                }
            } else {
                int tc = t - 1;
                if (tc >= 0 && tc < T_) {  // L1-P1(tc)
                    int wid = wg - 32;
                    int bm0 = (wid & 3) * 32, bn0 = (wid >> 2) * 128;
                    int bm = bm0 + wr * 16, bc = bn0 + wc * 64;
                    const unsigned short* h0cur = (tc & 1) ? h0b1 : h0b0;
                    f32x4 acc[4] = {};
                    mfma_acc<1024>(acc, h0cur, h1b, w1rf, bm + lr, bc, lane);
                    #pragma unroll
                    for (int j = 0; j < 4; ++j) {
                        int col = bc + j * 16 + ccol;
                        int g = col >> 9, h = col & 511;
                        float bias = bh[1536 + g * 512 + h];
                        #pragma unroll
                        for (int r = 0; r < 4; ++r) {
                            int b = bm + crow0 + r;
                            float v = acc[j][r] + bias;
                            float sg = 1.f / (1.f + __expf(-v));
                            if (g == 0) rh1b[b * 512 + h] = f2bf(sg * h1f[b * 512 + h]);
                            else        f1buf[b * 512 + h] = sg;
                        }
                    }
                }
            }
        } else {
            int t = s >> 1;
            if (wg < 16) {
                if (t < T_) {  // L0-P2(t): candidate + blend
                    int bm0 = (wg & 3) * 32, bn0 = (wg >> 2) * 128;
                    int bm = bm0 + wr * 16, bc = bn0 + wc * 64;
                    unsigned short* h0bw = (t & 1) ? h0b1 : h0b0;
                    f32x4 acc[4] = {};
                    mfma_acc<512>(acc, rh0b, rh0b, whl0c, bm + lr, bc, lane);
                    #pragma unroll
                    for (int j = 0; j < 4; ++j) {
                        int h = bc + j * 16 + ccol;
                        float bias = bh[1024 + h];
                        const float* gx = gx0 + (size_t)(t * 3 + 2) * BH_ + h;
                        #pragma unroll
                        for (int r = 0; r < 4; ++r) {
                            int b = bm + crow0 + r;
                            float v = acc[j][r] + gx[b * 512] + bias;
                            float tld = tanhf(v);
                            float hp = h0f[b * 512 + h];
                            float f = f0buf[b * 512 + h];
                            float hn = hp + f * (tld - hp);
                            h0f[b * 512 + h] = hn;
                            h0bw[b * 512 + h] = f2bf(hn);
                        }
                    }
                }
            } else if (wg < 32) {
                int tc = t - 1;
                if (tc >= 0 && tc < T_) {  // L1-P2(tc)
                    int wid = wg - 16;
                    int bm0 = (wid & 3) * 32, bn0 = (wid >> 2) * 128;
                    int bm = bm0 + wr * 16, bc = bn0 + wc * 64;
                    const unsigned short* h0cur = (tc & 1) ? h0b1 : h0b0;
                    f32x4 acc[4] = {};
                    mfma_acc<1024>(acc, h0cur, rh1b, w1c, bm + lr, bc, lane);
                    #pragma unroll
                    for (int j = 0; j < 4; ++j) {
                        int h = bc + j * 16 + ccol;
                        float bias = bh[2560 + h];
                        #pragma unroll
                        for (int r = 0; r < 4; ++r) {
                            int b = bm + crow0 + r;
                            float v = acc[j][r] + bias;
                            float tld = tanhf(v);
                            float hp = h1f[b * 512 + h];
                            float f = f1buf[b * 512 + h];
                            float hn = hp + f * (tld - hp);
                            h1f[b * 512 + h] = hn;
                            unsigned short hb = f2bf(hn);
                            h1b[b * 512 + h] = hb;
                            h1bf[(size_t)tc * BH_ + b * 512 + h] = hb;
                        }
                    }
                }
            }
        }
        grid_bar(bar, s + 1);
    }

    // final hidden state -> out tail (h0f/h1f final after last barrier)
    for (int i = wg * 256 + threadIdx.x; i < BH_; i += NWG * 256) {
        hfinal_out[i] = h0f[i];
        hfinal_out[BH_ + i] = h1f[i];
    }
}

// ---------------------------------------------------------------- logits
__global__ __launch_bounds__(256) void logits_gemm(
    const unsigned short* __restrict__ A, const float* __restrict__ Wout,
    const float* __restrict__ bout, float* __restrict__ C) {
    const int K = H_;
    int m0 = blockIdx.x * 128, n0 = blockIdx.y * 128;
    int wave = threadIdx.x >> 6, lane = threadIdx.x & 63;
    int wr = wave >> 1, wc = wave & 1;
    int am = m0 + wr * 64, bn = n0 + wc * 64;
    int lr = lane & 15, lk = (lane >> 4) * 8;

    f32x4 acc[4][4] = {};
    for (int k0 = 0; k0 < K; k0 += 32) {
        bf16x8 a[4], b[4];
        #pragma unroll
        for (int i = 0; i < 4; ++i)
            a[i] = *(const bf16x8*)(A + (size_t)(am + i * 16 + lr) * K + k0 + lk);
        #pragma unroll
        for (int j = 0; j < 4; ++j) {
            int colc = bn + j * 16 + lr; if (colc >= V_) colc = V_ - 1;
            const float* wp = Wout + (size_t)colc * K + k0 + lk;
            float4 w0 = *(const float4*)wp;
            float4 w1 = *(const float4*)(wp + 4);
            bf16x8 bb;
            bb[0] = (short)f2bf(w0.x); bb[1] = (short)f2bf(w0.y);
            bb[2] = (short)f2bf(w0.z); bb[3] = (short)f2bf(w0.w);
            bb[4] = (short)f2bf(w1.x); bb[5] = (short)f2bf(w1.y);
            bb[6] = (short)f2bf(w1.z); bb[7] = (short)f2bf(w1.w);
            b[j] = bb;
        }
        #pragma unroll
        for (int i = 0; i < 4; ++i)
            #pragma unroll
            for (int j = 0; j < 4; ++j)
                acc[i][j] = __builtin_amdgcn_mfma_f32_16x16x32_bf16(a[i], b[j], acc[i][j], 0, 0, 0);
    }
    int crow0 = (lane >> 4) * 4, ccol = lane & 15;
    #pragma unroll
    for (int j = 0; j < 4; ++j) {
        int col = bn + j * 16 + ccol;
        if (col >= V_) continue;
        float bv = bout[col];
        #pragma unroll
        for (int i = 0; i < 4; ++i) {
            #pragma unroll
            for (int r = 0; r < 4; ++r) {
                int row = am + i * 16 + crow0 + r;
                __builtin_nontemporal_store(acc[i][j][r] + bv, &C[(size_t)row * V_ + col]);
            }
        }
    }
}

// ---------------------------------------------------------------- launch
extern "C" void kernel_launch(void* const* d_in, const int* in_sizes, int n_in,
                              void* d_out, int out_size, void* d_ws, size_t ws_size,
                              hipStream_t stream) {
    const int*   inputs = (const int*)  d_in[0];
    const float* hidden = (const float*)d_in[1];
    const float* emb    = (const float*)d_in[2];
    const float* Wx0    = (const float*)d_in[3];
    const float* Wx     = (const float*)d_in[4];
    const float* Wh     = (const float*)d_in[5];
    const float* bh     = (const float*)d_in[6];
    const float* Wout   = (const float*)d_in[7];
    const float* bout   = (const float*)d_in[8];
    float* out = (float*)d_out;
    (void)in_sizes; (void)n_in; (void)out_size; (void)ws_size;

    char* ws = (char*)d_ws;
    size_t off = 0;
    auto alloc = [&](size_t bytes) -> void* {
        void* p = ws + off;
        off += (bytes + 255) & ~(size_t)255;
        return p;
    };
    unsigned short* embB   = (unsigned short*)alloc((size_t)V_ * KPAD * 2);
    unsigned short* wx0cat = (unsigned short*)alloc((size_t)1536 * KPAD * 2);
    unsigned short* whl0rf = (unsigned short*)alloc((size_t)1024 * 512 * 2);
    unsigned short* whl0c  = (unsigned short*)alloc((size_t)512 * 512 * 2);
    unsigned short* w1rf   = (unsigned short*)alloc((size_t)1024 * 1024 * 2);
    unsigned short* w1c    = (unsigned short*)alloc((size_t)512 * 1024 * 2);
    unsigned short* h1bf   = (unsigned short*)alloc((size_t)T_ * BH_ * 2);
    float* h0f  = (float*)alloc(BH_ * 4);
    float* h1f  = (float*)alloc(BH_ * 4);
    unsigned short* h0b0 = (unsigned short*)alloc(BH_ * 2);
    unsigned short* h0b1 = (unsigned short*)alloc(BH_ * 2);
    unsigned short* h1b  = (unsigned short*)alloc(BH_ * 2);
    unsigned short* rh0b = (unsigned short*)alloc(BH_ * 2);
    unsigned short* rh1b = (unsigned short*)alloc(BH_ * 2);
    float* f0buf = (float*)alloc(BH_ * 4);
    float* f1buf = (float*)alloc(BH_ * 4);
    int* bar = (int*)alloc(256);

    // gx0 [T][3][128][512] f32 lives in d_out (27.5 MB); overwritten by logits later.
    float* gx0 = out;

    prep_all<<<dim3(1024, 7), dim3(256), 0, stream>>>(
        emb, Wx0, Wx, Wh, hidden, embB, wx0cat, whl0rf, whl0c, w1rf, w1c,
        h0f, h0b1, h1f, h1b, bar);
    xside_gemm<<<dim3(T_, 12), dim3(256), 0, stream>>>(inputs, embB, wx0cat, gx0);
    scan_kernel<<<dim3(NWG), dim3(256), 0, stream>>>(
        gx0, whl0rf, whl0c, w1rf, w1c, bh,
        h0f, h0b0, h0b1, h1f, h1b, rh0b, f0buf, rh1b, f1buf, h1bf, bar,
        out + (size_t)T_ * B_ * V_);
    logits_gemm<<<dim3(T_ * B_ / 128, (V_ + 127) / 128), dim3(256), 0, stream>>>(
        h1bf, Wout, bout, out);
}